// Round 1
// 268.060 us; speedup vs baseline: 1.0104x; 1.0104x over previous
//
#include <hip/hip_runtime.h>

typedef unsigned short ushort_t;
typedef __attribute__((ext_vector_type(8))) __bf16 bf16x8;
typedef __attribute__((ext_vector_type(4))) float f32x4;

// B=32, N=128, INDIM=32, OUTDIM=64
// X: [32][128][128][32] f32; W: [32][64]; bias: [64]; n_nodes: [32] int
// X1t: [32][64][128][128] bf16  plane rows i, k=j contiguous
// X2t: [32][64][128][128] bf16  plane rows j, k=i contiguous
// Ct : [32][64][128][128] bf16  plane [i][j], aliases X1t (per-plane exclusive)
// out: [32][128][128][64] f32
//
// Masking contract (changed from "producer writes exact zeros"):
//  - K1 writes ONLY rows r < n and col-parts part*32 < n (== the [0,kmax)
//    window K2 reads). Rows in [n,ceil16(n)) are ws poison; garbage in an
//    A-row j only contaminates C row j>=n, garbage B-row i only C col i>=n.
//  - K2 stores ONLY i < n rows and j-chunks c*8 < n (== what K3 reads).
//  - K3 masks j >= n inside the boundary chunk on load (keystone that makes
//    this bit-identical to full-zero-fill compute).

__device__ __forceinline__ ushort_t f32_to_bf16(float v) {
    unsigned ui = __float_as_uint(v);
    ui += 0x7fffu + ((ui >> 16) & 1u);   // RNE (finite only)
    return (ushort_t)(ui >> 16);
}

union FragU { bf16x8 f; ushort_t u[8]; };
union Pack4 { ushort_t us[4]; uint2 v; };

// K1 (merged passes): Linear(32->64)+bias+ReLU+mask via mfma_16x16x32.
// Grid 2048: blocks 0..1023 pass A (r=i, t=j contiguous), 1024..2047 pass B
// (r=j, t=i strided). Each block handles 4 consecutive r. r>=n rows are
// skipped entirely (no zero-fill); t-tiles>=n skip loads+MFMA; copy-out
// truncated to col-parts < ceil32(n).
__global__ __launch_bounds__(256) void lin_mfma_kernel(
        const float* __restrict__ X,
        const float* __restrict__ W1, const float* __restrict__ b1v,
        const float* __restrict__ W2, const float* __restrict__ b2v,
        const int* __restrict__ n_nodes,
        ushort_t* __restrict__ X1t, ushort_t* __restrict__ X2t) {
    __shared__ ushort_t sO[64 * 136];
    const int blk = blockIdx.x;
    const int pass = blk >> 10;
    const int idx = blk & 1023;
    const int b = idx >> 5, rg = idx & 31;           // r-group of 4
    const int n = n_nodes[b];
    if (rg * 4 >= n) return;                         // block-uniform: nothing to write

    const float* W    = pass ? W2  : W1;
    const float* bias = pass ? b2v : b1v;
    ushort_t* Out     = pass ? X2t : X1t;
    const int rstride = pass ? 32 : 4096;
    const int tstride = pass ? 4096 : 32;

    const int u = threadIdx.x;
    const int w = u >> 6, l = u & 63;
    const int quad = l >> 4, lid = l & 15;

    // B-fragments: B[n=e][k=d], lane holds e=ni*16+lid, d=quad*8+j (L1-hot W).
    FragU bfrag[4];
    float bia[4];
    #pragma unroll
    for (int ni = 0; ni < 4; ++ni) {
        const int e = ni * 16 + lid;
        #pragma unroll
        for (int j = 0; j < 8; ++j)
            bfrag[ni].u[j] = f32_to_bf16(W[(quad * 8 + j) * 64 + e]);
        bia[ni] = bias[e];
    }

    for (int q = 0; q < 4; ++q) {
        const int r = rg * 4 + q;
        if (r >= n) break;                           // uniform (r ascending)
        {
            const float* Xb = X + (size_t)b * 524288 + (size_t)r * rstride;
            #pragma unroll
            for (int s = 0; s < 2; ++s) {
                const int mt = w * 2 + s;           // wave w owns m-tiles 2w,2w+1
                const int t0b = mt * 16 + quad * 4;
                if (mt * 16 < n) {
                    const int m = mt * 16 + lid;
                    const float* xr = Xb + (size_t)m * tstride + quad * 8;
                    float4 x0 = *(const float4*)xr;
                    float4 x1 = *(const float4*)(xr + 4);
                    FragU af;
                    af.u[0] = f32_to_bf16(x0.x); af.u[1] = f32_to_bf16(x0.y);
                    af.u[2] = f32_to_bf16(x0.z); af.u[3] = f32_to_bf16(x0.w);
                    af.u[4] = f32_to_bf16(x1.x); af.u[5] = f32_to_bf16(x1.y);
                    af.u[6] = f32_to_bf16(x1.z); af.u[7] = f32_to_bf16(x1.w);
                    #pragma unroll
                    for (int ni = 0; ni < 4; ++ni) {
                        f32x4 acc = {};
                        acc = __builtin_amdgcn_mfma_f32_16x16x32_bf16(
                            af.f, bfrag[ni].f, acc, 0, 0, 0);
                        const int e = ni * 16 + lid;
                        Pack4 pk;
                        #pragma unroll
                        for (int rgi = 0; rgi < 4; ++rgi) {
                            const int t = t0b + rgi;
                            float v = (t < n) ? fmaxf(acc[rgi] + bia[ni], 0.f) : 0.f;
                            pk.us[rgi] = f32_to_bf16(v);
                        }
                        *(uint2*)(sO + e * 136 + t0b) = pk.v;
                    }
                } else {
                    Pack4 pk; pk.us[0] = pk.us[1] = pk.us[2] = pk.us[3] = 0;
                    #pragma unroll
                    for (int ni = 0; ni < 4; ++ni)
                        *(uint2*)(sO + (ni * 16 + lid) * 136 + t0b) = pk.v;
                }
            }
        }
        __syncthreads();
        {   // copy-out: 64 e-rows, only col-parts < ceil32(n) (what K2 reads)
            const int e = u >> 2, part = u & 3;
            if (part * 32 < n) {
                ushort_t* gO = Out + ((size_t)(b * 64 + e) * 128 + r) * 128 + part * 32;
                const ushort_t* sRow = sO + e * 136 + part * 32;
                #pragma unroll
                for (int c = 0; c < 4; ++c)
                    *(uint4*)(gO + c * 8) = *(const uint4*)(sRow + c * 8);
            }
        }
        __syncthreads();
    }
}

// K2: per-(b,e) 128x128x128 bf16 MFMA, direct-from-global frags. k-loop
// truncated at ceil(n/32)*32; j-tiles/i-tiles >= n skip loads+MFMA. Rows in
// [n,ceil16(n)) are garbage (K1 no longer zero-fills) -> contaminate only
// C[i>=n][*] and C[*][j>=n], which are either not stored or masked in K3.
// Epilogue stores only i<n rows, j-chunks c*8<n (exactly what K3 reads).
__global__ __launch_bounds__(256) void mm_kernel(
        const ushort_t* __restrict__ X1t, const ushort_t* __restrict__ X2t,
        ushort_t* __restrict__ Ct, const int* __restrict__ n_nodes) {
    __shared__ ushort_t sC[128 * 136];
    const int blk = blockIdx.x;
    const size_t plane = (size_t)blk * 16384;        // blk = b*64+e
    const int n = n_nodes[blk >> 6];
    const int kmax = (n + 31) & ~31;
    const ushort_t* Aj = X2t + plane;
    const ushort_t* Bi = X1t + plane;
    const int u = threadIdx.x;
    const int w = u >> 6, l = u & 63;
    const int quad = l >> 4, lid = l & 15;
    const int wj = (w >> 1) * 64, wi = (w & 1) * 64;
    const bool anyA = (wj < n), anyB = (wi < n);
    bool aAct[4], bAct[4];
    #pragma unroll
    for (int mj = 0; mj < 4; ++mj) aAct[mj] = (wj + mj * 16) < n;
    #pragma unroll
    for (int ni = 0; ni < 4; ++ni) bAct[ni] = (wi + ni * 16) < n;
    f32x4 acc[4][4] = {};                            // [mj][ni]

    for (int k0 = 0; k0 < kmax; k0 += 32) {
        bf16x8 af[4], bfr[4];
        #pragma unroll
        for (int mj = 0; mj < 4; ++mj)
            if (aAct[mj] && anyB)
                af[mj] = *(const bf16x8*)(Aj + (size_t)(wj + mj * 16 + lid) * 128 + k0 + quad * 8);
        #pragma unroll
        for (int ni = 0; ni < 4; ++ni)
            if (bAct[ni] && anyA)
                bfr[ni] = *(const bf16x8*)(Bi + (size_t)(wi + ni * 16 + lid) * 128 + k0 + quad * 8);
        #pragma unroll
        for (int mj = 0; mj < 4; ++mj)
            #pragma unroll
            for (int ni = 0; ni < 4; ++ni)
                if (aAct[mj] && bAct[ni])
                    acc[mj][ni] = __builtin_amdgcn_mfma_f32_16x16x32_bf16(
                        af[mj], bfr[ni], acc[mj][ni], 0, 0, 0);
    }

    #pragma unroll
    for (int mj = 0; mj < 4; ++mj)
        #pragma unroll
        for (int ni = 0; ni < 4; ++ni) {
            const int j0 = wj + mj * 16 + quad * 4;  // C row = j (reg-contiguous)
            const int i  = wi + ni * 16 + lid;       // C col = i
            Pack4 pk;
            #pragma unroll
            for (int rg = 0; rg < 4; ++rg)
                pk.us[rg] = f32_to_bf16(acc[mj][ni][rg]);
            *(uint2*)(sC + i * 136 + j0) = pk.v;
        }
    __syncthreads();
    ushort_t* Cp = Ct + plane;
    #pragma unroll
    for (int it = 0; it < 8; ++it) {
        int idx = it * 256 + u;
        int i = idx >> 4, c = idx & 15;
        if (i < n && c * 8 < n)
            *(uint4*)(Cp + (size_t)idx * 8) = *(const uint4*)(sC + i * 136 + c * 8);
    }
}

// K3: block = (b, i). i>=n: write 32 KB zeros, no reads. Else gather
// Ct[b][e][i][j<n] (coalesced) into LDS sT[e][j] f32 stride 129, masking
// j>=n inside the boundary chunk and zero-filling j-tail chunks, then write
// out[b][i][:][:] as one contiguous 32-KB region.
__global__ __launch_bounds__(256) void tr_kernel(
        const ushort_t* __restrict__ Ct, float* __restrict__ out,
        const int* __restrict__ n_nodes) {
    __shared__ float sT[64 * 129];
    const int blk = blockIdx.x;                      // b*128 + i
    const int b = blk >> 7, i = blk & 127;
    const int u = threadIdx.x;
    const int n = n_nodes[b];
    float* ob = out + ((size_t)b * 16384 + (size_t)i * 128) * 64;

    if (i >= n) {                                    // block-uniform early-out
        float4 z = {0.f, 0.f, 0.f, 0.f};
        #pragma unroll
        for (int it = 0; it < 8; ++it)
            *(float4*)(ob + (size_t)(it * 256 + u) * 4) = z;
        return;
    }

    const ushort_t* Cb = Ct + (size_t)b * 1048576 + (size_t)i * 128;
    #pragma unroll
    for (int it = 0; it < 4; ++it) {
        int idx = it * 256 + u;
        int e = idx >> 4, c = idx & 15;
        float* dst = sT + e * 129 + c * 8;
        const int rem = n - c * 8;                   // #valid j in this chunk
        if (rem >= 8) {
            uint4 v = *(const uint4*)(Cb + (size_t)e * 16384 + c * 8);
            dst[0] = __uint_as_float(v.x << 16);
            dst[1] = __uint_as_float(v.x & 0xffff0000u);
            dst[2] = __uint_as_float(v.y << 16);
            dst[3] = __uint_as_float(v.y & 0xffff0000u);
            dst[4] = __uint_as_float(v.z << 16);
            dst[5] = __uint_as_float(v.z & 0xffff0000u);
            dst[6] = __uint_as_float(v.w << 16);
            dst[7] = __uint_as_float(v.w & 0xffff0000u);
        } else if (rem > 0) {                        // boundary chunk: mask j>=n
            uint4 v = *(const uint4*)(Cb + (size_t)e * 16384 + c * 8);
            float tmp[8];
            tmp[0] = __uint_as_float(v.x << 16);
            tmp[1] = __uint_as_float(v.x & 0xffff0000u);
            tmp[2] = __uint_as_float(v.y << 16);
            tmp[3] = __uint_as_float(v.y & 0xffff0000u);
            tmp[4] = __uint_as_float(v.z << 16);
            tmp[5] = __uint_as_float(v.z & 0xffff0000u);
            tmp[6] = __uint_as_float(v.w << 16);
            tmp[7] = __uint_as_float(v.w & 0xffff0000u);
            #pragma unroll
            for (int t = 0; t < 8; ++t) dst[t] = (t < rem) ? tmp[t] : 0.f;
        } else {
            #pragma unroll
            for (int t = 0; t < 8; ++t) dst[t] = 0.f;
        }
    }
    __syncthreads();

    #pragma unroll
    for (int it = 0; it < 8; ++it) {
        int idx = it * 256 + u;                      // float4 over flat (j,e)
        int j = idx >> 4, e0 = (idx & 15) * 4;
        float4 vv;
        vv.x = sT[(e0 + 0) * 129 + j];
        vv.y = sT[(e0 + 1) * 129 + j];
        vv.z = sT[(e0 + 2) * 129 + j];
        vv.w = sT[(e0 + 3) * 129 + j];
        *(float4*)(ob + (size_t)idx * 4) = vv;
    }
}

extern "C" void kernel_launch(void* const* d_in, const int* in_sizes, int n_in,
                              void* d_out, int out_size, void* d_ws, size_t ws_size,
                              hipStream_t stream) {
    const float* X  = (const float*)d_in[0];
    const float* W1 = (const float*)d_in[1];
    const float* b1 = (const float*)d_in[2];
    const float* W2 = (const float*)d_in[3];
    const float* b2 = (const float*)d_in[4];
    const int* nn   = (const int*)d_in[5];
    float* out = (float*)d_out;

    ushort_t* X1t = (ushort_t*)d_ws;          // 64 MiB
    ushort_t* X2t = X1t + 33554432;           // +64 MiB
    ushort_t* Ct  = X1t;                      // alias (per-plane exclusive in K2)

    lin_mfma_kernel<<<2048, 256, 0, stream>>>(X, W1, b1, W2, b2, nn, X1t, X2t);
    mm_kernel<<<2048, 256, 0, stream>>>(X1t, X2t, Ct, nn);
    tr_kernel<<<4096, 256, 0, stream>>>(Ct, out, nn);
}